// Round 4
// baseline (108.386 us; speedup 1.0000x reference)
//
#include <hip/hip_runtime.h>

#define NF 40
#define ED 128
#define NB 1024
#define NIX 780
#define XROW (NF * ED)      // 5120
#define KROW (NIX * ED)     // 99840
#define XB_BYTES (NB * NF * ED * 2)   // 13,107,200
#define KB_BYTES (NIX * ED * ED * 2)  // 25,559,040
#define WS_NEED (XB_BYTES + KB_BYTES)

typedef __attribute__((ext_vector_type(8))) short bf16x8;
typedef __attribute__((ext_vector_type(4))) float f32x4;
typedef __attribute__((ext_vector_type(4))) unsigned short ushx4;
typedef __attribute__((ext_vector_type(8))) unsigned short ushx8;

__device__ __forceinline__ unsigned short f2bf(float x) {
  unsigned int u = __float_as_uint(x);
  u = (u + 0x7FFFu + ((u >> 16) & 1u)) >> 16;
  return (unsigned short)u;
}
__device__ __forceinline__ float bf2f(unsigned short h) {
  return __uint_as_float(((unsigned int)h) << 16);
}

#define GLOAD16(gsrc, ldst)                                                    \
  __builtin_amdgcn_global_load_lds(                                            \
      (const __attribute__((address_space(1))) void*)(gsrc),                   \
      (__attribute__((address_space(3))) void*)(ldst), 16, 0, 0)

// ---- fused prepass: x fp32->bf16 (blocks 0..2559), K [e][n][d]->[n][e][d] bf16 ----
__global__ void cvt_fused(const float* __restrict__ x, const float* __restrict__ kr,
                          unsigned short* __restrict__ xb, unsigned short* __restrict__ kb) {
  const int blk = blockIdx.x;
  if (blk < 2560) {
    const size_t g = ((size_t)blk * 256 + threadIdx.x) * 8;
    float4 a = *reinterpret_cast<const float4*>(x + g);
    float4 b = *reinterpret_cast<const float4*>(x + g + 4);
    ushx8 h;
    h[0] = f2bf(a.x); h[1] = f2bf(a.y); h[2] = f2bf(a.z); h[3] = f2bf(a.w);
    h[4] = f2bf(b.x); h[5] = f2bf(b.y); h[6] = f2bf(b.z); h[7] = f2bf(b.w);
    *reinterpret_cast<ushx8*>(xb + g) = h;
  } else {
    const size_t g = ((size_t)(blk - 2560) * 256 + threadIdx.x) * 4;
    const int d = (int)(g & 127);
    const size_t t = g >> 7;
    const int e = (int)(t & 127);
    const int n = (int)(t >> 7);
    float4 v = *reinterpret_cast<const float4*>(kr + ((size_t)e * NIX + n) * ED + d);
    ushx4 h;
    h[0] = f2bf(v.x); h[1] = f2bf(v.y); h[2] = f2bf(v.z); h[3] = f2bf(v.w);
    *reinterpret_cast<ushx4*>(kb + g) = h;
  }
}

// ------------- main kernel: barrier-free register streaming -------------
__launch_bounds__(256, 2)
__global__ void opn_ws(const unsigned short* __restrict__ xb,
                       const unsigned short* __restrict__ kb,
                       float* __restrict__ out) {
  __shared__ unsigned short Klds[ED * ED];  // 32 KB, K only, read-only after stage

  const int n = blockIdx.x;
  const int tid = threadIdx.x;
  const int lane = tid & 63;
  const int w = tid >> 6;
  const int lm = lane & 15;
  const int lq = lane >> 4;

  // pair (fi, fj)
  int fi = 0, base = 0;
  while (base + (NF - 1 - fi) <= n) { base += NF - 1 - fi; ++fi; }
  const int fj = fi + 1 + (n - base);

  // ---- stage K (32 KB) via global_load_lds, pre-swizzled source ----
  {
    const unsigned short* ks = kb + (size_t)n * (ED * ED);
    const int col8 = lm * 8;
    #pragma unroll
    for (int j = 0; j < 8; ++j) {
      const int chunk = j * 4 + w;           // 0..31, 1KB each
      const int r = chunk * 4 + lq;          // 0..127
      const int c = col8 ^ ((r & 7) << 3);
      GLOAD16(ks + r * ED + c, Klds + chunk * 512);
    }
  }
  __syncthreads();  // one-time: K fully in LDS

  // ---- hoist K as MFMA A-fragments: A[m=e][k=d], e = f*16+lm, d = kk*32+lq*8+j ----
  bf16x8 afr[4][8];
  #pragma unroll
  for (int kk = 0; kk < 4; ++kk)
    #pragma unroll
    for (int f = 0; f < 8; ++f) {
      const int r = f * 16 + lm;
      afr[kk][f] = *reinterpret_cast<const bf16x8*>(
          &Klds[r * ED + ((kk * 32 + lq * 8) ^ ((r & 7) << 3))]);
    }
  #pragma unroll
  for (int kk = 0; kk < 4; ++kk)
    #pragma unroll
    for (int f = 0; f < 8; ++f)
      asm volatile("" : "+v"(afr[kk][f]));   // pin: forbid remat from LDS
  // no further barriers: Klds is never overwritten, waves run free

  const int prow = w * 16 + lm;              // this lane's b row within tile
  const int row0 = blockIdx.y * 512 + prow;
  const unsigned short* pP = xb + (size_t)fi * ED + (size_t)row0 * XROW + lq * 8;
  const unsigned short* pQ = xb + (size_t)fj * ED + (size_t)row0 * XROW + lq * 4;
  float* po = out + (size_t)row0 * NIX + n;

  // P B-fragment direct from global: 16B contiguous per kk (bit-identical to LDS path)
  auto loadP = [&](bf16x8 (&pf)[4], int t) {
    const unsigned short* p = pP + (size_t)t * (64 * XROW);
    #pragma unroll
    for (int kk = 0; kk < 4; ++kk)
      pf[kk] = *reinterpret_cast<const bf16x8*>(p + kk * 32);
  };

  auto body = [&](bf16x8 (&pf)[4], int t) {
    // issue Q loads first; they complete under the MFMA phase
    const unsigned short* q = pQ + (size_t)t * (64 * XROW);
    ushx4 qv[8];
    #pragma unroll
    for (int f = 0; f < 8; ++f)
      qv[f] = *reinterpret_cast<const ushx4*>(q + f * 16);

    f32x4 acc[8];
    #pragma unroll
    for (int f = 0; f < 8; ++f) acc[f] = (f32x4){0.f, 0.f, 0.f, 0.f};
    #pragma unroll
    for (int kk = 0; kk < 4; ++kk)
      #pragma unroll
      for (int f = 0; f < 8; ++f)
        acc[f] = __builtin_amdgcn_mfma_f32_16x16x32_bf16(afr[kk][f], pf[kk], acc[f], 0, 0, 0);

    // dot over e: lane holds T[e=f*16+lq*4+r][b=prow]; Q[b=prow][same e]
    float s = 0.f;
    #pragma unroll
    for (int f = 0; f < 8; ++f)
      #pragma unroll
      for (int r = 0; r < 4; ++r)
        s = fmaf(acc[f][r], bf2f(qv[f][r]), s);
    s += __shfl_xor(s, 16);
    s += __shfl_xor(s, 32);
    if (lane < 16) po[(size_t)t * (64 * NIX)] = s;
  };

  // software pipeline, static double reg-set (rule #20: no runtime indexing)
  bf16x8 pA[4], pB[4];
  loadP(pA, 0);
  #pragma unroll 1
  for (int t = 0; t < 8; t += 2) {
    loadP(pB, t + 1);
    body(pA, t);
    if (t + 2 < 8) loadP(pA, t + 2);
    body(pB, t + 1);
  }
}

// ---------------- fallback (proven Round-1 kernel, used when ws too small) ----------------
__device__ __forceinline__ int swz_fb(int row, int col) {
  return row * 128 + (col ^ ((row & 7) << 3));
}

__launch_bounds__(256, 2)
__global__ void opn_fb(const float* __restrict__ x,
                       const float* __restrict__ kern,
                       float* __restrict__ out) {
  __shared__ unsigned short Klds[128 * 128];
  __shared__ unsigned short Plds[64 * 128];
  __shared__ unsigned short Qlds[64 * 132];

  const int n = blockIdx.x;
  const int tid = threadIdx.x;
  const int lane = tid & 63;
  const int w = tid >> 6;
  const int lm = lane & 15;
  const int lq = lane >> 4;

  int fi = 0, base = 0;
  while (base + (NF - 1 - fi) <= n) { base += NF - 1 - fi; ++fi; }
  const int fj = fi + 1 + (n - base);

  {
    const int r8 = tid >> 5;
    const int d0 = (tid & 31) * 4;
    const float* kbp = kern + (size_t)n * ED + d0;
    #pragma unroll
    for (int p = 0; p < 16; ++p) {
      int e = p * 8 + r8;
      float4 v = *reinterpret_cast<const float4*>(kbp + (size_t)e * KROW);
      ushx4 h;
      h[0] = f2bf(v.x); h[1] = f2bf(v.y); h[2] = f2bf(v.z); h[3] = f2bf(v.w);
      *reinterpret_cast<ushx4*>(&Klds[swz_fb(e, d0)]) = h;
    }
  }
  __syncthreads();

  bf16x8 bfr[4][8];
  #pragma unroll
  for (int kk = 0; kk < 4; ++kk)
    #pragma unroll
    for (int f = 0; f < 8; ++f)
      bfr[kk][f] = *reinterpret_cast<const bf16x8*>(
          &Klds[swz_fb(f * 16 + lm, kk * 32 + lq * 8)]);

  const int r8 = tid >> 5;
  const int c4 = (tid & 31) * 4;

  for (int t = 0; t < 8; ++t) {
    const int b0 = blockIdx.y * 512 + t * 64;
    __syncthreads();
    #pragma unroll
    for (int p = 0; p < 8; ++p) {
      int r = p * 8 + r8;
      const float* xbp = x + (size_t)(b0 + r) * XROW + c4;
      float4 vp = *reinterpret_cast<const float4*>(xbp + fi * ED);
      ushx4 hp;
      hp[0] = f2bf(vp.x); hp[1] = f2bf(vp.y); hp[2] = f2bf(vp.z); hp[3] = f2bf(vp.w);
      *reinterpret_cast<ushx4*>(&Plds[swz_fb(r, c4)]) = hp;
      float4 vq = *reinterpret_cast<const float4*>(xbp + fj * ED);
      ushx4 hq;
      hq[0] = f2bf(vq.x); hq[1] = f2bf(vq.y); hq[2] = f2bf(vq.z); hq[3] = f2bf(vq.w);
      *reinterpret_cast<ushx4*>(&Qlds[r * 132 + c4]) = hq;
    }
    __syncthreads();

    f32x4 acc[8];
    #pragma unroll
    for (int f = 0; f < 8; ++f) acc[f] = (f32x4){0.f, 0.f, 0.f, 0.f};
    #pragma unroll
    for (int kk = 0; kk < 4; ++kk) {
      bf16x8 a = *reinterpret_cast<const bf16x8*>(
          &Plds[swz_fb(w * 16 + lm, kk * 32 + lq * 8)]);
      #pragma unroll
      for (int f = 0; f < 8; ++f)
        acc[f] = __builtin_amdgcn_mfma_f32_16x16x32_bf16(a, bfr[kk][f], acc[f], 0, 0, 0);
    }

    #pragma unroll
    for (int r = 0; r < 4; ++r) {
      const int bl = w * 16 + lq * 4 + r;
      float s = 0.f;
      #pragma unroll
      for (int f = 0; f < 8; ++f)
        s = fmaf(acc[f][r], bf2f(Qlds[bl * 132 + f * 16 + lm]), s);
      s += __shfl_xor(s, 1);
      s += __shfl_xor(s, 2);
      s += __shfl_xor(s, 4);
      s += __shfl_xor(s, 8);
      if (lm == 0) out[(size_t)(b0 + bl) * NIX + n] = s;
    }
  }
}

extern "C" void kernel_launch(void* const* d_in, const int* in_sizes, int n_in,
                              void* d_out, int out_size, void* d_ws, size_t ws_size,
                              hipStream_t stream) {
  const float* x = (const float*)d_in[0];
  const float* kern = (const float*)d_in[1];
  float* out = (float*)d_out;
  (void)in_sizes; (void)n_in; (void)out_size;

  if (ws_size >= (size_t)WS_NEED) {
    unsigned short* xb = (unsigned short*)d_ws;
    unsigned short* kbuf = (unsigned short*)((char*)d_ws + XB_BYTES);
    cvt_fused<<<15040, 256, 0, stream>>>(x, kern, xb, kbuf);  // 2560 x-blocks + 12480 k-blocks
    dim3 grid(NIX, 2, 1);
    opn_ws<<<grid, 256, 0, stream>>>(xb, kbuf, out);
  } else {
    dim3 grid(NIX, 2, 1);
    opn_fb<<<grid, 256, 0, stream>>>(x, kern, out);
  }
}

// Round 6
// 74.500 us; speedup vs baseline: 1.4548x; 1.4548x over previous
//
#include <hip/hip_runtime.h>

#define NF 40
#define ED 128
#define NB 1024
#define NIX 780
#define XROW (NF * ED)      // 5120
#define KROW (NIX * ED)     // 99840
#define XB_BYTES (NB * NF * ED * 2)   // 13,107,200
#define KB_BYTES (NIX * ED * ED * 2)  // 25,559,040
#define WS_NEED (XB_BYTES + KB_BYTES)

typedef __attribute__((ext_vector_type(8))) short bf16x8;
typedef __attribute__((ext_vector_type(4))) float f32x4;
typedef __attribute__((ext_vector_type(4))) unsigned short ushx4;
typedef __attribute__((ext_vector_type(8))) unsigned short ushx8;

__device__ __forceinline__ unsigned short f2bf(float x) {
  unsigned int u = __float_as_uint(x);
  u = (u + 0x7FFFu + ((u >> 16) & 1u)) >> 16;
  return (unsigned short)u;
}
__device__ __forceinline__ float bf2f(unsigned short h) {
  return __uint_as_float(((unsigned int)h) << 16);
}

#define GLOAD16(gsrc, ldst)                                                    \
  __builtin_amdgcn_global_load_lds(                                            \
      (const __attribute__((address_space(1))) void*)(gsrc),                   \
      (__attribute__((address_space(3))) void*)(ldst), 16, 0, 0)

// ---- fused prepass: x fp32->bf16 (blocks 0..2559), K [e][n][d]->[n][e][d] bf16 ----
__global__ void cvt_fused(const float* __restrict__ x, const float* __restrict__ kr,
                          unsigned short* __restrict__ xb, unsigned short* __restrict__ kb) {
  const int blk = blockIdx.x;
  if (blk < 2560) {
    const size_t g = ((size_t)blk * 256 + threadIdx.x) * 8;
    float4 a = *reinterpret_cast<const float4*>(x + g);
    float4 b = *reinterpret_cast<const float4*>(x + g + 4);
    ushx8 h;
    h[0] = f2bf(a.x); h[1] = f2bf(a.y); h[2] = f2bf(a.z); h[3] = f2bf(a.w);
    h[4] = f2bf(b.x); h[5] = f2bf(b.y); h[6] = f2bf(b.z); h[7] = f2bf(b.w);
    *reinterpret_cast<ushx8*>(xb + g) = h;
  } else {
    const size_t g = ((size_t)(blk - 2560) * 256 + threadIdx.x) * 4;
    const int d = (int)(g & 127);
    const size_t t = g >> 7;
    const int e = (int)(t & 127);
    const int n = (int)(t >> 7);
    float4 v = *reinterpret_cast<const float4*>(kr + ((size_t)e * NIX + n) * ED + d);
    ushx4 h;
    h[0] = f2bf(v.x); h[1] = f2bf(v.y); h[2] = f2bf(v.z); h[3] = f2bf(v.w);
    *reinterpret_cast<ushx4*>(kb + g) = h;
  }
}

// ---- main kernel: e-split across warps, 32-row b-tiles, 4 blocks/CU ----
__launch_bounds__(256, 4)
__global__ void opn_ws(const unsigned short* __restrict__ xb,
                       const unsigned short* __restrict__ kb,
                       float* __restrict__ out) {
  // 32 KB: K staging first; after hoist reused as P[0..4095] + Q[4096..8191]
  __shared__ unsigned short S[16384];
  __shared__ float scratch[4][32];   // per-warp partial dots

  const int n = blockIdx.x;
  const int tid = threadIdx.x;
  const int lane = tid & 63;
  const int w = tid >> 6;
  const int lm = lane & 15;
  const int lq = lane >> 4;
  const int col8 = lm * 8;

  // pair (fi, fj)
  int fi = 0, base = 0;
  while (base + (NF - 1 - fi) <= n) { base += NF - 1 - fi; ++fi; }
  const int fj = fi + 1 + (n - base);

  // ---- stage K (32 KB) via global_load_lds, pre-swizzled source ----
  {
    const unsigned short* ks = kb + (size_t)n * (ED * ED);
    #pragma unroll
    for (int j = 0; j < 8; ++j) {
      const int chunk = j * 4 + w;           // 0..31, 1KB each
      const int r = chunk * 4 + lq;          // 0..127
      const int c = col8 ^ ((r & 7) << 3);
      GLOAD16(ks + r * ED + c, S + chunk * 512);
    }
  }
  __syncthreads();

  // ---- hoist this warp's e-quarter: A[m=e][k=d], e = w*32 + f*16 + lm ----
  bf16x8 afr[4][2];
  #pragma unroll
  for (int kk = 0; kk < 4; ++kk)
    #pragma unroll
    for (int f = 0; f < 2; ++f) {
      const int r = w * 32 + f * 16 + lm;
      afr[kk][f] = *reinterpret_cast<const bf16x8*>(
          &S[r * ED + ((kk * 32 + lq * 8) ^ ((r & 7) << 3))]);
    }
  #pragma unroll
  for (int kk = 0; kk < 4; ++kk)
    #pragma unroll
    for (int f = 0; f < 2; ++f)
      asm volatile("" : "+v"(afr[kk][f]));   // pin: forbid remat from LDS
  __syncthreads();                            // all warps done reading K area

  unsigned short* Plds = S;                   // 8 KB
  unsigned short* Qlds = S + 4096;            // 8 KB

  const int b0base = blockIdx.y * 256;

  #pragma unroll 1
  for (int t = 0; t < 8; ++t) {
    const int b0 = b0base + t * 32;

    // ---- stage P,Q (4 loads/thread, 16 KB) ----
    #pragma unroll
    for (int j = 0; j < 2; ++j) {
      const int chunk = j * 4 + w;           // 0..7
      const int r = chunk * 4 + lq;          // 0..31
      const int c = col8 ^ ((r & 7) << 3);
      const size_t xoff = (size_t)(b0 + r) * XROW + c;
      GLOAD16(xb + xoff + (size_t)fi * ED, Plds + chunk * 512);
      GLOAD16(xb + xoff + (size_t)fj * ED, Qlds + chunk * 512);
    }
    __syncthreads();   // full drain: tile staged

    // ---- T-quarter = K_w @ P^T : D[m=e][col=b], nt = b-subtile ----
    f32x4 acc[2][2];
    #pragma unroll
    for (int f = 0; f < 2; ++f)
      #pragma unroll
      for (int nt = 0; nt < 2; ++nt)
        acc[f][nt] = (f32x4){0.f, 0.f, 0.f, 0.f};

    __builtin_amdgcn_s_setprio(1);
    #pragma unroll
    for (int kk = 0; kk < 4; ++kk) {
      #pragma unroll
      for (int nt = 0; nt < 2; ++nt) {
        const int pb = nt * 16 + lm;
        bf16x8 pfr = *reinterpret_cast<const bf16x8*>(
            &Plds[pb * ED + ((kk * 32 + lq * 8) ^ ((pb & 7) << 3))]);
        #pragma unroll
        for (int f = 0; f < 2; ++f)
          acc[f][nt] = __builtin_amdgcn_mfma_f32_16x16x32_bf16(afr[kk][f], pfr, acc[f][nt], 0, 0, 0);
      }
    }
    __builtin_amdgcn_s_setprio(0);

    // ---- partial dot over this warp's e-quarter ----
    // lane holds T[e = w*32 + f*16 + lq*4 + r][b = nt*16 + lm]
    float s[2];
    #pragma unroll
    for (int nt = 0; nt < 2; ++nt) {
      const int qrow = nt * 16 + lm;
      float t0 = 0.f, t1 = 0.f, t2 = 0.f, t3 = 0.f;
      #pragma unroll
      for (int f = 0; f < 2; ++f) {
        const int c = (w * 32 + f * 16 + lq * 4) ^ ((qrow & 7) << 3);
        ushx4 q4 = *reinterpret_cast<const ushx4*>(&Qlds[qrow * ED + c]);
        t0 = fmaf(acc[f][nt][0], bf2f(q4[0]), t0);
        t1 = fmaf(acc[f][nt][1], bf2f(q4[1]), t1);
        t2 = fmaf(acc[f][nt][2], bf2f(q4[2]), t2);
        t3 = fmaf(acc[f][nt][3], bf2f(q4[3]), t3);
      }
      float sv = (t0 + t1) + (t2 + t3);
      sv += __shfl_xor(sv, 16);   // sum over lq groups (e-sub-quarters)
      sv += __shfl_xor(sv, 32);
      s[nt] = sv;
    }
    if (lq == 0) {                // lanes 0..15 of each warp
      scratch[w][lm] = s[0];
      scratch[w][16 + lm] = s[1];
    }
    __syncthreads();              // scratch ready; all tile reads done

    if (tid < 32) {               // cross-warp reduce + store
      const int b = tid;
      float r = (scratch[0][b] + scratch[1][b]) + (scratch[2][b] + scratch[3][b]);
      out[(size_t)(b0 + b) * NIX + n] = r;
    }
    // next iteration's stage may start immediately: it writes Plds/Qlds
    // (all reads of which completed before the barrier above), and the next
    // scratch write is separated from this read by the next barrier.
  }
}

// ---------------- fallback (proven Round-1 kernel, used when ws too small) ----------------
__device__ __forceinline__ int swz_fb(int row, int col) {
  return row * 128 + (col ^ ((row & 7) << 3));
}

__launch_bounds__(256, 2)
__global__ void opn_fb(const float* __restrict__ x,
                       const float* __restrict__ kern,
                       float* __restrict__ out) {
  __shared__ unsigned short Klds[128 * 128];
  __shared__ unsigned short Plds[64 * 128];
  __shared__ unsigned short Qlds[64 * 132];

  const int n = blockIdx.x;
  const int tid = threadIdx.x;
  const int lane = tid & 63;
  const int w = tid >> 6;
  const int lm = lane & 15;
  const int lq = lane >> 4;

  int fi = 0, base = 0;
  while (base + (NF - 1 - fi) <= n) { base += NF - 1 - fi; ++fi; }
  const int fj = fi + 1 + (n - base);

  {
    const int r8 = tid >> 5;
    const int d0 = (tid & 31) * 4;
    const float* kbp = kern + (size_t)n * ED + d0;
    #pragma unroll
    for (int p = 0; p < 16; ++p) {
      int e = p * 8 + r8;
      float4 v = *reinterpret_cast<const float4*>(kbp + (size_t)e * KROW);
      ushx4 h;
      h[0] = f2bf(v.x); h[1] = f2bf(v.y); h[2] = f2bf(v.z); h[3] = f2bf(v.w);
      *reinterpret_cast<ushx4*>(&Klds[swz_fb(e, d0)]) = h;
    }
  }
  __syncthreads();

  bf16x8 bfr[4][8];
  #pragma unroll
  for (int kk = 0; kk < 4; ++kk)
    #pragma unroll
    for (int f = 0; f < 8; ++f)
      bfr[kk][f] = *reinterpret_cast<const bf16x8*>(
          &Klds[swz_fb(f * 16 + lm, kk * 32 + lq * 8)]);

  const int r8 = tid >> 5;
  const int c4 = (tid & 31) * 4;

  for (int t = 0; t < 8; ++t) {
    const int b0 = blockIdx.y * 512 + t * 64;
    __syncthreads();
    #pragma unroll
    for (int p = 0; p < 8; ++p) {
      int r = p * 8 + r8;
      const float* xbp = x + (size_t)(b0 + r) * XROW + c4;
      float4 vp = *reinterpret_cast<const float4*>(xbp + fi * ED);
      ushx4 hp;
      hp[0] = f2bf(vp.x); hp[1] = f2bf(vp.y); hp[2] = f2bf(vp.z); hp[3] = f2bf(vp.w);
      *reinterpret_cast<ushx4*>(&Plds[swz_fb(r, c4)]) = hp;
      float4 vq = *reinterpret_cast<const float4*>(xbp + fj * ED);
      ushx4 hq;
      hq[0] = f2bf(vq.x); hq[1] = f2bf(vq.y); hq[2] = f2bf(vq.z); hq[3] = f2bf(vq.w);
      *reinterpret_cast<ushx4*>(&Qlds[r * 132 + c4]) = hq;
    }
    __syncthreads();

    f32x4 acc[8];
    #pragma unroll
    for (int f = 0; f < 8; ++f) acc[f] = (f32x4){0.f, 0.f, 0.f, 0.f};
    #pragma unroll
    for (int kk = 0; kk < 4; ++kk) {
      bf16x8 a = *reinterpret_cast<const bf16x8*>(
          &Plds[swz_fb(w * 16 + lm, kk * 32 + lq * 8)]);
      #pragma unroll
      for (int f = 0; f < 8; ++f)
        acc[f] = __builtin_amdgcn_mfma_f32_16x16x32_bf16(a, bfr[kk][f], acc[f], 0, 0, 0);
    }

    #pragma unroll
    for (int r = 0; r < 4; ++r) {
      const int bl = w * 16 + lq * 4 + r;
      float s = 0.f;
      #pragma unroll
      for (int f = 0; f < 8; ++f)
        s = fmaf(acc[f][r], bf2f(Qlds[bl * 132 + f * 16 + lm]), s);
      s += __shfl_xor(s, 1);
      s += __shfl_xor(s, 2);
      s += __shfl_xor(s, 4);
      s += __shfl_xor(s, 8);
      if (lm == 0) out[(size_t)(b0 + bl) * NIX + n] = s;
    }
  }
}

extern "C" void kernel_launch(void* const* d_in, const int* in_sizes, int n_in,
                              void* d_out, int out_size, void* d_ws, size_t ws_size,
                              hipStream_t stream) {
  const float* x = (const float*)d_in[0];
  const float* kern = (const float*)d_in[1];
  float* out = (float*)d_out;
  (void)in_sizes; (void)n_in; (void)out_size;

  if (ws_size >= (size_t)WS_NEED) {
    unsigned short* xb = (unsigned short*)d_ws;
    unsigned short* kbuf = (unsigned short*)((char*)d_ws + XB_BYTES);
    cvt_fused<<<15040, 256, 0, stream>>>(x, kern, xb, kbuf);
    dim3 grid(NIX, 4, 1);
    opn_ws<<<grid, 256, 0, stream>>>(xb, kbuf, out);
  } else {
    dim3 grid(NIX, 2, 1);
    opn_fb<<<grid, 256, 0, stream>>>(x, kern, out);
  }
}